// Round 10
// baseline (1763.512 us; speedup 1.0000x reference)
//
#include <hip/hip_runtime.h>
#include <float.h>

#define N_NODES 100000
#define N_EDGES 3200000
#define N_GRAPHS 1024
#define F_IN 78
#define H 128
#define BN_EPS 1e-5f

#define BK_SHIFT 7
#define BK_NODES 128
#define NBUCKETS ((N_NODES + BK_NODES - 1) / BK_NODES)  // 782

#define P3_BLOCKS 200
#define P3_CHUNK 16000  // 200 * 16000 = 3.2M exactly

using short8 = __attribute__((ext_vector_type(8))) short;
using f32x4v = __attribute__((ext_vector_type(4))) float;

__device__ __forceinline__ unsigned short f2bf(float f) {
    unsigned int u = __float_as_uint(f);
    unsigned int r = (u + 0x7fffu + ((u >> 16) & 1u)) >> 16;
    return (unsigned short)r;
}
__device__ __forceinline__ float bf_lo(unsigned int u) { return __uint_as_float(u << 16); }
__device__ __forceinline__ float bf_hi(unsigned int u) { return __uint_as_float(u & 0xffff0000u); }
__device__ __forceinline__ float bf1(unsigned short u) { return __uint_as_float((unsigned int)u << 16); }

// ---------------- CSR build (atomic-free partition) ----------------

__global__ __launch_bounds__(256) void k_hist(const int* __restrict__ dst,
                                              int* __restrict__ bofs) {
    __shared__ int lcnt[NBUCKETS];
    for (int i = threadIdx.x; i < NBUCKETS; i += 256) lcnt[i] = 0;
    __syncthreads();
    int base = blockIdx.x * P3_CHUNK;
    for (int j = threadIdx.x; j < P3_CHUNK; j += 256)
        atomicAdd(&lcnt[dst[base + j] >> BK_SHIFT], 1);
    __syncthreads();
    for (int i = threadIdx.x; i < NBUCKETS; i += 256)
        bofs[blockIdx.x * NBUCKETS + i] = lcnt[i];
}

__global__ __launch_bounds__(256) void k_scan_a(int* __restrict__ bofs,
                                                int* __restrict__ btot) {
    __shared__ int part[256];
    int b = blockIdx.x, t = threadIdx.x;
    int val = (t < P3_BLOCKS) ? bofs[t * NBUCKETS + b] : 0;
    part[t] = val;
    __syncthreads();
    if (t == 0) {
        int run = 0;
        for (int u = 0; u < P3_BLOCKS; ++u) { int tmp = part[u]; part[u] = run; run += tmp; }
        btot[b] = run;
    }
    __syncthreads();
    if (t < P3_BLOCKS) bofs[t * NBUCKETS + b] = part[t];
}

__global__ __launch_bounds__(1024) void k_scan_b(const int* __restrict__ btot,
                                                 int* __restrict__ bbase,
                                                 int* __restrict__ row_start) {
    __shared__ int tot[1024];
    int t = threadIdx.x;
    tot[t] = (t < NBUCKETS) ? btot[t] : 0;
    __syncthreads();
    if (t == 0) {
        int acc = 0;
        for (int i = 0; i < NBUCKETS; ++i) { int v = tot[i]; tot[i] = acc; acc += v; }
    }
    __syncthreads();
    if (t < NBUCKETS) bbase[t] = tot[t];
    if (t == 0) {
        bbase[NBUCKETS] = N_EDGES;
        row_start[N_NODES] = N_EDGES;
    }
}

__global__ __launch_bounds__(256) void k_p3b(const int* __restrict__ src,
                                             const int* __restrict__ dst,
                                             const int* __restrict__ bofs,
                                             const int* __restrict__ bbase,
                                             unsigned int* __restrict__ ebuf) {
    __shared__ int cur[NBUCKETS];
    for (int i = threadIdx.x; i < NBUCKETS; i += 256)
        cur[i] = bbase[i] + bofs[blockIdx.x * NBUCKETS + i];
    __syncthreads();
    int base = blockIdx.x * P3_CHUNK;
    for (int j = threadIdx.x; j < P3_CHUNK; j += 256) {
        int d = dst[base + j];
        int p = atomicAdd(&cur[d >> BK_SHIFT], 1);
        ebuf[p] = ((unsigned int)src[base + j] << 7) | (unsigned int)(d & (BK_NODES - 1));
    }
}

__global__ __launch_bounds__(256) void k_p4(const int* __restrict__ bbase,
                                            const unsigned int* __restrict__ ebuf,
                                            int* __restrict__ esrc,
                                            int* __restrict__ row_start) {
    __shared__ int cur[BK_NODES];
    __shared__ int start[BK_NODES];
    int b = blockIdx.x;
    int nodeBase = b << BK_SHIFT;
    int nLocal = min(BK_NODES, N_NODES - nodeBase);
    if (threadIdx.x < BK_NODES) cur[threadIdx.x] = 0;
    __syncthreads();
    int s = bbase[b], e = bbase[b + 1];
    for (int p = s + threadIdx.x; p < e; p += 256)
        atomicAdd(&cur[ebuf[p] & (BK_NODES - 1)], 1);
    __syncthreads();
    if (threadIdx.x == 0) {
        int run = s;
        for (int i = 0; i < nLocal; ++i) { start[i] = run; run += cur[i]; }
    }
    __syncthreads();
    if (threadIdx.x < nLocal) {
        row_start[nodeBase + threadIdx.x] = start[threadIdx.x];
        cur[threadIdx.x] = start[threadIdx.x];
    }
    __syncthreads();
    for (int p = s + threadIdx.x; p < e; p += 256) {
        unsigned int ed = ebuf[p];
        int q = atomicAdd(&cur[ed & (BK_NODES - 1)], 1);
        esrc[q] = (int)(ed >> 7);
    }
}

// ---------------- bf16 prep ----------------

__global__ void k_cast_x(const float* __restrict__ x, unsigned short* __restrict__ xb) {
    int i = blockIdx.x * blockDim.x + threadIdx.x;
    if (i >= N_NODES * 96) return;
    int node = i / 96;
    int c = i - node * 96;
    float v = (c < F_IN) ? x[(size_t)node * F_IN + c] : 0.f;
    xb[i] = f2bf(v);
}

__global__ void k_cast_w(const float* __restrict__ W2_0, const float* __restrict__ W1,
                         const float* __restrict__ W2, unsigned short* __restrict__ Wt) {
    int i = blockIdx.x * blockDim.x + threadIdx.x;
    if (i >= 9 * H * H) return;
    int w = i >> 14, r = i & 16383;
    int n = r >> 7, k = r & 127;
    const float* s = (w == 0) ? W2_0 : (w <= 4 ? W1 + (w - 1) * H * H : W2 + (w - 5) * H * H);
    Wt[i] = f2bf(s[k * H + n]);
}

__global__ void k_cast_w0(const float* __restrict__ W1_0, unsigned short* __restrict__ Wt0) {
    int i = blockIdx.x * blockDim.x + threadIdx.x;
    if (i >= H * 96) return;
    int n = i / 96, k = i - n * 96;
    Wt0[i] = f2bf((k < F_IN) ? W1_0[k * H + n] : 0.f);
}

// ---------------- gather (aggregate) kernels ----------------

// layer 0: xb bf16 [N][96] row-major (48 dwords); out = self+agg bf16 [N][96]
__global__ void k_gather96(const unsigned int* __restrict__ xw,
                           const int* __restrict__ row_start, const int* __restrict__ esrc,
                           unsigned int* __restrict__ out) {
    int wave = threadIdx.x >> 6;
    int lane = threadIdx.x & 63;
    int node = blockIdx.x * 4 + wave;
    int s = row_start[node], e = row_start[node + 1];
    bool act = lane < 48;
    unsigned int su = act ? xw[node * 48 + lane] : 0u;
    float aA[8], aB[8];
#pragma unroll
    for (int j = 0; j < 8; ++j) { aA[j] = 0.f; aB[j] = 0.f; }
    aA[0] = bf_lo(su); aB[0] = bf_hi(su);
    int p = s;
    for (; p + 16 <= e; p += 16) {
        int idx[16];
#pragma unroll
        for (int j = 0; j < 16; ++j) idx[j] = esrc[p + j];
        unsigned int u[16];
#pragma unroll
        for (int j = 0; j < 16; ++j) u[j] = act ? xw[idx[j] * 48 + lane] : 0u;
#pragma unroll
        for (int j = 0; j < 16; ++j) { aA[j & 7] += bf_lo(u[j]); aB[j & 7] += bf_hi(u[j]); }
    }
    for (; p + 4 <= e; p += 4) {
        int i0 = esrc[p], i1 = esrc[p + 1], i2 = esrc[p + 2], i3 = esrc[p + 3];
        unsigned int u0 = act ? xw[i0 * 48 + lane] : 0u;
        unsigned int u1 = act ? xw[i1 * 48 + lane] : 0u;
        unsigned int u2 = act ? xw[i2 * 48 + lane] : 0u;
        unsigned int u3 = act ? xw[i3 * 48 + lane] : 0u;
        aA[0] += bf_lo(u0); aB[0] += bf_hi(u0); aA[1] += bf_lo(u1); aB[1] += bf_hi(u1);
        aA[2] += bf_lo(u2); aB[2] += bf_hi(u2); aA[3] += bf_lo(u3); aB[3] += bf_hi(u3);
    }
    for (; p < e; ++p) {
        unsigned int u = act ? xw[esrc[p] * 48 + lane] : 0u;
        aA[0] += bf_lo(u); aB[0] += bf_hi(u);
    }
    if (act) {
        float rx = ((aA[0] + aA[1]) + (aA[2] + aA[3])) + ((aA[4] + aA[5]) + (aA[6] + aA[7]));
        float ry = ((aB[0] + aB[1]) + (aB[2] + aB[3])) + ((aB[4] + aB[5]) + (aB[6] + aB[7]));
        out[node * 48 + lane] = (unsigned int)f2bf(rx) | ((unsigned int)f2bf(ry) << 16);
    }
}

// layers 1..4: feature-sliced gather. hbs/aggs layout: [slice][node][8 u32] (16 bf16 cols).
// slice = blockIdx.x & 7 -> pins each slice to one XCD (round-robin heuristic);
// per-slice working set = 3.2 MB -> fits 4 MiB per-XCD L2.
// lane = 8*eoff + c: 8 edges in parallel, 8 dwords each; shfl_xor reduce over eoff.
__global__ void k_gather_s(const unsigned int* __restrict__ hbs,
                           const int* __restrict__ row_start, const int* __restrict__ esrc,
                           unsigned int* __restrict__ aggs) {
    int wave = threadIdx.x >> 6;
    int lane = threadIdx.x & 63;
    int slice = blockIdx.x & 7;
    int node = (blockIdx.x >> 3) * 4 + wave;
    int c = lane & 7, eoff = lane >> 3;
    const unsigned int* __restrict__ base = hbs + (size_t)slice * N_NODES * 8;
    int s = row_start[node], e = row_start[node + 1];
    float a0 = 0.f, b0 = 0.f, a1 = 0.f, b1 = 0.f;
    int p = s;
    for (; p + 16 <= e; p += 16) {
        int i0 = esrc[p + eoff];
        int i1 = esrc[p + 8 + eoff];
        unsigned int u0 = base[(size_t)i0 * 8 + c];
        unsigned int u1 = base[(size_t)i1 * 8 + c];
        a0 += bf_lo(u0); b0 += bf_hi(u0);
        a1 += bf_lo(u1); b1 += bf_hi(u1);
    }
    if (p + 8 <= e) {
        int i0 = esrc[p + eoff];
        unsigned int u0 = base[(size_t)i0 * 8 + c];
        a0 += bf_lo(u0); b0 += bf_hi(u0);
        p += 8;
    }
    if (p + eoff < e) {
        int i0 = esrc[p + eoff];
        unsigned int u0 = base[(size_t)i0 * 8 + c];
        a1 += bf_lo(u0); b1 += bf_hi(u0);
    }
    float ax = a0 + a1, bx = b0 + b1;
    ax += __shfl_xor(ax, 8);  bx += __shfl_xor(bx, 8);
    ax += __shfl_xor(ax, 16); bx += __shfl_xor(bx, 16);
    ax += __shfl_xor(ax, 32); bx += __shfl_xor(bx, 32);
    if (eoff == 0) {
        unsigned int su = base[(size_t)node * 8 + c];
        float rx = bf_lo(su) + ax;
        float ry = bf_hi(su) + bx;
        aggs[(size_t)slice * N_NODES * 8 + (size_t)node * 8 + c] =
            (unsigned int)f2bf(rx) | ((unsigned int)f2bf(ry) << 16);
    }
}

// ---------------- fused 2-GEMM MLP (MFMA, bf16) ----------------
// SLICED: A in [slice][node][16 bf16] layout; else row-major [node][K1].

template <int NK1, bool SLICED>
__global__ __launch_bounds__(256) void k_mlp(const short* __restrict__ A,
                                             const short* __restrict__ Wt1,
                                             const float* __restrict__ b1v,
                                             const short* __restrict__ Wt2,
                                             const float* __restrict__ b2v,
                                             unsigned short* __restrict__ out,
                                             float* __restrict__ gsum,
                                             float* __restrict__ gss) {
    const int K1 = NK1 * 32;
    __shared__ unsigned short act1[64 * H];  // 16 KB
    __shared__ float lsum[H], lss[H];
    if (threadIdx.x < H) { lsum[threadIdx.x] = 0.f; lss[threadIdx.x] = 0.f; }
    int wave = threadIdx.x >> 6, lane = threadIdx.x & 63;
    int r0 = blockIdx.x * 64 + wave * 16;
    int lm = lane & 15, lk = lane >> 4;
    int arow = r0 + lm;
    if (arow >= N_NODES) arow = N_NODES - 1;
    const short8* Arow = (const short8*)(A + (size_t)arow * K1);
    f32x4v acc[8];
#pragma unroll
    for (int n = 0; n < 8; ++n) {
        float bv = b1v[n * 16 + lm];
        acc[n] = (f32x4v){bv, bv, bv, bv};
    }
#pragma unroll
    for (int ks = 0; ks < NK1; ++ks) {
        short8 af;
        if constexpr (SLICED) {
            int sl = 2 * ks + (lk >> 1);
            af = *(const short8*)(A + ((size_t)sl * N_NODES + arow) * 16 + (lk & 1) * 8);
        } else {
            af = Arow[ks * 4 + lk];
        }
#pragma unroll
        for (int n = 0; n < 8; ++n) {
            const short8* Brow = (const short8*)(Wt1 + (size_t)(n * 16 + lm) * K1);
            short8 bfr = Brow[ks * 4 + lk];
            acc[n] = __builtin_amdgcn_mfma_f32_16x16x32_bf16(af, bfr, acc[n], 0, 0, 0);
        }
    }
#pragma unroll
    for (int n = 0; n < 8; ++n) {
        int colb = (n * 16 + lm) * 2;
#pragma unroll
        for (int rg = 0; rg < 4; ++rg) {
            int rl = wave * 16 + lk * 4 + rg;
            int byte = (rl * 256 + colb) ^ ((rl & 7) << 4);
            *(unsigned short*)((char*)act1 + byte) = f2bf(fmaxf(acc[n][rg], 0.f));
        }
    }
    __syncthreads();
    f32x4v acc2[8];
#pragma unroll
    for (int n = 0; n < 8; ++n) {
        float bv = b2v[n * 16 + lm];
        acc2[n] = (f32x4v){bv, bv, bv, bv};
    }
    int rlr = wave * 16 + lm;
#pragma unroll
    for (int ks = 0; ks < 4; ++ks) {
        int byte = (rlr * 256 + ks * 64 + lk * 16) ^ ((rlr & 7) << 4);
        short8 af = *(const short8*)((char*)act1 + byte);
#pragma unroll
        for (int n = 0; n < 8; ++n) {
            const short8* Brow = (const short8*)(Wt2 + (size_t)(n * 16 + lm) * H);
            short8 bfr = Brow[ks * 4 + lk];
            acc2[n] = __builtin_amdgcn_mfma_f32_16x16x32_bf16(af, bfr, acc2[n], 0, 0, 0);
        }
    }
#pragma unroll
    for (int n = 0; n < 8; ++n) {
        int col = n * 16 + lm;
        float s = 0.f, q = 0.f;
#pragma unroll
        for (int rg = 0; rg < 4; ++rg) {
            int r = r0 + lk * 4 + rg;
            if (r < N_NODES) {
                float v = fmaxf(acc2[n][rg], 0.f);
                out[(size_t)r * H + col] = f2bf(v);
                s += v;
                q += v * v;
            }
        }
        atomicAdd(&lsum[col], s);
        atomicAdd(&lss[col], q);
    }
    __syncthreads();
    if (threadIdx.x < H) {
        atomicAdd(&gsum[threadIdx.x], lsum[threadIdx.x]);
        atomicAdd(&gss[threadIdx.x], lss[threadIdx.x]);
    }
}

// ---------------- BN ----------------

__global__ void k_bnfinal(float* __restrict__ gsum, float* __restrict__ gss,
                          const float* __restrict__ gamma, const float* __restrict__ beta,
                          float* __restrict__ scale, float* __restrict__ shift) {
    int c = threadIdx.x;
    const float inv_n = 1.f / (float)N_NODES;
    float sv = gsum[c], qv = gss[c];
    gsum[c] = 0.f;
    gss[c] = 0.f;
    float mu = sv * inv_n;
    float var = fmaxf(qv * inv_n - mu * mu, 0.f);
    float sc = gamma[c] * rsqrtf(var + BN_EPS);
    scale[c] = sc;
    shift[c] = beta[c] - mu * sc;
}

// hbs = bf16( (RES? bf(hbs):0) + bf(act)*scale + shift ), sliced layout
template <bool RES>
__global__ void k_bnapply(const uint2* __restrict__ vb, const float* __restrict__ scale,
                          const float* __restrict__ shift, uint2* __restrict__ hbs) {
    int idx = blockIdx.x * blockDim.x + threadIdx.x;  // 4-elem index
    if (idx >= N_NODES * H / 4) return;
    int c4 = idx & 31;
    int node = idx >> 5;
    size_t hidx = ((size_t)(c4 >> 2) * N_NODES + node) * 4 + (c4 & 3);
    uint2 pv = vb[idx];
    float4 val = make_float4(bf_lo(pv.x), bf_hi(pv.x), bf_lo(pv.y), bf_hi(pv.y));
    float4 sc = reinterpret_cast<const float4*>(scale)[c4];
    float4 sh = reinterpret_cast<const float4*>(shift)[c4];
    float4 r;
    r.x = val.x * sc.x + sh.x;
    r.y = val.y * sc.y + sh.y;
    r.z = val.z * sc.z + sh.z;
    r.w = val.w * sc.w + sh.w;
    if (RES) {
        uint2 hv = hbs[hidx];
        r.x += bf_lo(hv.x); r.y += bf_hi(hv.x); r.z += bf_lo(hv.y); r.w += bf_hi(hv.y);
    }
    uint2 pk;
    pk.x = (unsigned int)f2bf(r.x) | ((unsigned int)f2bf(r.y) << 16);
    pk.y = (unsigned int)f2bf(r.z) | ((unsigned int)f2bf(r.w) << 16);
    hbs[hidx] = pk;
}

// ---------------- pooling + head ----------------

__global__ void k_bounds(const int* __restrict__ batch, int* __restrict__ row_begin) {
    int i = blockIdx.x * blockDim.x + threadIdx.x;
    if (i >= N_NODES) return;
    int bi = batch[i];
    int bp = (i == 0) ? -1 : batch[i - 1];
    for (int g = bp + 1; g <= bi; ++g) row_begin[g] = i;
    if (i == N_NODES - 1) {
        for (int g = bi + 1; g <= N_GRAPHS; ++g) row_begin[g] = N_NODES;
    }
}

// fused: h4 = bf(hbs3) + scale*bf(act) + shift on the fly, then mean/max pool
__global__ void k_pool_f(const unsigned short* __restrict__ act, const float* __restrict__ scale,
                         const float* __restrict__ shift, const unsigned int* __restrict__ hbs,
                         const int* __restrict__ row_begin, float* __restrict__ pooled) {
    int g = blockIdx.x;
    int c = threadIdx.x;  // 128
    float sc = scale[c], sh = shift[c];
    size_t sbase = (size_t)(c >> 4) * N_NODES * 8 + ((c >> 1) & 7);
    int odd = c & 1;
    int s = row_begin[g], e = row_begin[g + 1];
    float sum = 0.f, mx = -FLT_MAX;
    for (int i = s; i < e; ++i) {
        unsigned int u = hbs[sbase + (size_t)i * 8];
        float hv = odd ? bf_hi(u) : bf_lo(u);
        float v = hv + sc * bf1(act[(size_t)i * H + c]) + sh;
        sum += v;
        mx = fmaxf(mx, v);
    }
    int cnt = e - s;
    pooled[g * 256 + c]       = (cnt > 0) ? sum / (float)cnt : 0.f;
    pooled[g * 256 + 128 + c] = (cnt > 0) ? mx : 0.f;
}

__global__ void k_final(const float* __restrict__ pooled, const float* __restrict__ Wf,
                        const float* __restrict__ bf, float* __restrict__ out) {
    __shared__ float ps[256];
    int g = blockIdx.x, c = threadIdx.x;
    ps[c] = pooled[g * 256 + c];
    ps[128 + c] = pooled[g * 256 + 128 + c];
    __syncthreads();
    float acc = bf[c];
#pragma unroll 8
    for (int k = 0; k < 256; ++k) acc += ps[k] * Wf[k * H + c];
    out[g * H + c] = acc;
}

// ---------------- launcher ----------------

extern "C" void kernel_launch(void* const* d_in, const int* in_sizes, int n_in,
                              void* d_out, int out_size, void* d_ws, size_t ws_size,
                              hipStream_t stream) {
    const float* x     = (const float*)d_in[0];
    const int*   ei    = (const int*)d_in[1];
    const int*   src   = ei;
    const int*   dst   = ei + N_EDGES;
    const int*   batch = (const int*)d_in[2];
    const float* W1_0  = (const float*)d_in[3];
    const float* b1_0  = (const float*)d_in[4];
    const float* W2_0  = (const float*)d_in[5];
    const float* b2_0  = (const float*)d_in[6];
    const float* W1    = (const float*)d_in[7];
    const float* b1    = (const float*)d_in[8];
    const float* W2    = (const float*)d_in[9];
    const float* b2    = (const float*)d_in[10];
    const float* gamma = (const float*)d_in[11];
    const float* beta  = (const float*)d_in[12];
    const float* Wf    = (const float*)d_in[13];
    const float* bf    = (const float*)d_in[14];
    float* out = (float*)d_out;

    char* ws = (char*)d_ws;
    size_t off = 0;
    auto alloc = [&](size_t bytes) -> void* {
        void* p = ws + off;
        off = (off + bytes + 255) & ~(size_t)255;
        return p;
    };

    uint2* hbs  = (uint2*)alloc((size_t)N_NODES * H * 2);        // sliced residual state
    unsigned int*   aggs  = (unsigned int*)alloc((size_t)N_NODES * H * 2);  // sliced agg
    unsigned short* act2b = (unsigned short*)alloc((size_t)N_NODES * H * 2);
    unsigned short* xb    = (unsigned short*)alloc((size_t)N_NODES * 96 * 2);
    unsigned int*   agg0b = (unsigned int*)alloc((size_t)N_NODES * 48 * 4);
    unsigned short* Wtall = (unsigned short*)alloc((size_t)9 * H * H * 2);
    unsigned short* Wt0   = (unsigned short*)alloc((size_t)H * 96 * 2);
    int* row_start = (int*)alloc((size_t)(N_NODES + 1) * 4);
    int* esrc      = (int*)alloc((size_t)N_EDGES * 4);
    unsigned int* ebuf = (unsigned int*)alloc((size_t)N_EDGES * 4);
    int* bofs      = (int*)alloc((size_t)P3_BLOCKS * NBUCKETS * 4);
    int* btot      = (int*)alloc((size_t)NBUCKETS * 4);
    int* bbase     = (int*)alloc((size_t)(NBUCKETS + 1) * 4);
    float* gsum  = (float*)alloc(H * 4);
    float* gss   = (float*)alloc(H * 4);
    float* scale = (float*)alloc(H * 4);
    float* shift = (float*)alloc(H * 4);
    int* row_begin = (int*)alloc((size_t)(N_GRAPHS + 1) * 4);
    float* pooled  = (float*)alloc((size_t)N_GRAPHS * 256 * 4);

    // ---- prep ----
    k_cast_x<<<(N_NODES * 96 + 255) / 256, 256, 0, stream>>>(x, xb);
    k_cast_w<<<(9 * H * H + 255) / 256, 256, 0, stream>>>(W2_0, W1, W2, Wtall);
    k_cast_w0<<<(H * 96 + 255) / 256, 256, 0, stream>>>(W1_0, Wt0);

    // ---- CSR build (no global atomics) ----
    k_hist<<<P3_BLOCKS, 256, 0, stream>>>(dst, bofs);
    k_scan_a<<<NBUCKETS, 256, 0, stream>>>(bofs, btot);
    k_scan_b<<<1, 1024, 0, stream>>>(btot, bbase, row_start);
    k_p3b<<<P3_BLOCKS, 256, 0, stream>>>(src, dst, bofs, bbase, ebuf);
    k_p4<<<NBUCKETS, 256, 0, stream>>>(bbase, ebuf, esrc, row_start);

    hipMemsetAsync(gsum, 0, H * 4, stream);
    hipMemsetAsync(gss, 0, H * 4, stream);

    const int mfma_grid = (N_NODES + 63) / 64;
    const int slice_grid = (N_NODES / 4) * 8;

    // ---- layer 0 (78 -> 128, no residual) ----
    k_gather96<<<N_NODES / 4, 256, 0, stream>>>((const unsigned int*)xb, row_start, esrc, agg0b);
    k_mlp<3, false><<<mfma_grid, 256, 0, stream>>>((const short*)agg0b, (const short*)Wt0, b1_0,
                                                   (const short*)Wtall, b2_0, act2b, gsum, gss);
    k_bnfinal<<<1, 128, 0, stream>>>(gsum, gss, gamma, beta, scale, shift);
    k_bnapply<false><<<N_NODES * H / 4 / 256, 256, 0, stream>>>((const uint2*)act2b,
                                                                scale, shift, hbs);

    // ---- layers 1..4 (residual) ----
    for (int l = 0; l < 4; ++l) {
        k_gather_s<<<slice_grid, 256, 0, stream>>>((const unsigned int*)hbs, row_start,
                                                   esrc, aggs);
        k_mlp<4, true><<<mfma_grid, 256, 0, stream>>>((const short*)aggs,
                                                      (const short*)(Wtall + (1 + l) * H * H),
                                                      b1 + l * H,
                                                      (const short*)(Wtall + (5 + l) * H * H),
                                                      b2 + l * H, act2b, gsum, gss);
        k_bnfinal<<<1, 128, 0, stream>>>(gsum, gss, gamma + (l + 1) * H, beta + (l + 1) * H,
                                         scale, shift);
        if (l < 3) {
            k_bnapply<true><<<N_NODES * H / 4 / 256, 256, 0, stream>>>((const uint2*)act2b,
                                                                       scale, shift, hbs);
        }
        // l == 3: bnapply fused into k_pool_f below
    }

    // ---- pooling + head ----
    k_bounds<<<(N_NODES + 255) / 256, 256, 0, stream>>>(batch, row_begin);
    k_pool_f<<<N_GRAPHS, 128, 0, stream>>>(act2b, scale, shift,
                                           (const unsigned int*)hbs, row_begin, pooled);
    k_final<<<N_GRAPHS, 128, 0, stream>>>(pooled, Wf, bf, out);
}

// Round 11
// 1221.512 us; speedup vs baseline: 1.4437x; 1.4437x over previous
//
#include <hip/hip_runtime.h>
#include <float.h>

#define N_NODES 100000
#define N_EDGES 3200000
#define N_GRAPHS 1024
#define F_IN 78
#define H 128
#define BN_EPS 1e-5f

#define BK_SHIFT 7
#define BK_NODES 128
#define NBUCKETS ((N_NODES + BK_NODES - 1) / BK_NODES)  // 782

#define P3_BLOCKS 200
#define P3_CHUNK 16000  // 200 * 16000 = 3.2M exactly

using short8 = __attribute__((ext_vector_type(8))) short;
using f32x4v = __attribute__((ext_vector_type(4))) float;

__device__ __forceinline__ unsigned short f2bf(float f) {
    unsigned int u = __float_as_uint(f);
    unsigned int r = (u + 0x7fffu + ((u >> 16) & 1u)) >> 16;
    return (unsigned short)r;
}
__device__ __forceinline__ float bf_lo(unsigned int u) { return __uint_as_float(u << 16); }
__device__ __forceinline__ float bf_hi(unsigned int u) { return __uint_as_float(u & 0xffff0000u); }
__device__ __forceinline__ float bf1(unsigned short u) { return __uint_as_float((unsigned int)u << 16); }

// ---------------- CSR build (atomic-free partition) ----------------

__global__ __launch_bounds__(256) void k_hist(const int* __restrict__ dst,
                                              int* __restrict__ bofs) {
    __shared__ int lcnt[NBUCKETS];
    for (int i = threadIdx.x; i < NBUCKETS; i += 256) lcnt[i] = 0;
    __syncthreads();
    int base = blockIdx.x * P3_CHUNK;
    for (int j = threadIdx.x; j < P3_CHUNK; j += 256)
        atomicAdd(&lcnt[dst[base + j] >> BK_SHIFT], 1);
    __syncthreads();
    for (int i = threadIdx.x; i < NBUCKETS; i += 256)
        bofs[blockIdx.x * NBUCKETS + i] = lcnt[i];
}

__global__ __launch_bounds__(256) void k_scan_a(int* __restrict__ bofs,
                                                int* __restrict__ btot) {
    __shared__ int part[256];
    int b = blockIdx.x, t = threadIdx.x;
    int val = (t < P3_BLOCKS) ? bofs[t * NBUCKETS + b] : 0;
    part[t] = val;
    __syncthreads();
    if (t == 0) {
        int run = 0;
        for (int u = 0; u < P3_BLOCKS; ++u) { int tmp = part[u]; part[u] = run; run += tmp; }
        btot[b] = run;
    }
    __syncthreads();
    if (t < P3_BLOCKS) bofs[t * NBUCKETS + b] = part[t];
}

__global__ __launch_bounds__(1024) void k_scan_b(const int* __restrict__ btot,
                                                 int* __restrict__ bbase,
                                                 int* __restrict__ row_start) {
    __shared__ int tot[1024];
    int t = threadIdx.x;
    tot[t] = (t < NBUCKETS) ? btot[t] : 0;
    __syncthreads();
    if (t == 0) {
        int acc = 0;
        for (int i = 0; i < NBUCKETS; ++i) { int v = tot[i]; tot[i] = acc; acc += v; }
    }
    __syncthreads();
    if (t < NBUCKETS) bbase[t] = tot[t];
    if (t == 0) {
        bbase[NBUCKETS] = N_EDGES;
        row_start[N_NODES] = N_EDGES;
    }
}

__global__ __launch_bounds__(256) void k_p3b(const int* __restrict__ src,
                                             const int* __restrict__ dst,
                                             const int* __restrict__ bofs,
                                             const int* __restrict__ bbase,
                                             unsigned int* __restrict__ ebuf) {
    __shared__ int cur[NBUCKETS];
    for (int i = threadIdx.x; i < NBUCKETS; i += 256)
        cur[i] = bbase[i] + bofs[blockIdx.x * NBUCKETS + i];
    __syncthreads();
    int base = blockIdx.x * P3_CHUNK;
    for (int j = threadIdx.x; j < P3_CHUNK; j += 256) {
        int d = dst[base + j];
        int p = atomicAdd(&cur[d >> BK_SHIFT], 1);
        ebuf[p] = ((unsigned int)src[base + j] << 7) | (unsigned int)(d & (BK_NODES - 1));
    }
}

__global__ __launch_bounds__(256) void k_p4(const int* __restrict__ bbase,
                                            const unsigned int* __restrict__ ebuf,
                                            int* __restrict__ esrc,
                                            int* __restrict__ row_start) {
    __shared__ int cur[BK_NODES];
    __shared__ int start[BK_NODES];
    int b = blockIdx.x;
    int nodeBase = b << BK_SHIFT;
    int nLocal = min(BK_NODES, N_NODES - nodeBase);
    if (threadIdx.x < BK_NODES) cur[threadIdx.x] = 0;
    __syncthreads();
    int s = bbase[b], e = bbase[b + 1];
    for (int p = s + threadIdx.x; p < e; p += 256)
        atomicAdd(&cur[ebuf[p] & (BK_NODES - 1)], 1);
    __syncthreads();
    if (threadIdx.x == 0) {
        int run = s;
        for (int i = 0; i < nLocal; ++i) { start[i] = run; run += cur[i]; }
    }
    __syncthreads();
    if (threadIdx.x < nLocal) {
        row_start[nodeBase + threadIdx.x] = start[threadIdx.x];
        cur[threadIdx.x] = start[threadIdx.x];
    }
    __syncthreads();
    for (int p = s + threadIdx.x; p < e; p += 256) {
        unsigned int ed = ebuf[p];
        int q = atomicAdd(&cur[ed & (BK_NODES - 1)], 1);
        esrc[q] = (int)(ed >> 7);
    }
}

// ---------------- bf16 prep ----------------

__global__ void k_cast_x(const float* __restrict__ x, unsigned short* __restrict__ xb) {
    int i = blockIdx.x * blockDim.x + threadIdx.x;
    if (i >= N_NODES * 96) return;
    int node = i / 96;
    int c = i - node * 96;
    float v = (c < F_IN) ? x[(size_t)node * F_IN + c] : 0.f;
    xb[i] = f2bf(v);
}

__global__ void k_cast_w(const float* __restrict__ W2_0, const float* __restrict__ W1,
                         const float* __restrict__ W2, unsigned short* __restrict__ Wt) {
    int i = blockIdx.x * blockDim.x + threadIdx.x;
    if (i >= 9 * H * H) return;
    int w = i >> 14, r = i & 16383;
    int n = r >> 7, k = r & 127;
    const float* s = (w == 0) ? W2_0 : (w <= 4 ? W1 + (w - 1) * H * H : W2 + (w - 5) * H * H);
    Wt[i] = f2bf(s[k * H + n]);
}

__global__ void k_cast_w0(const float* __restrict__ W1_0, unsigned short* __restrict__ Wt0) {
    int i = blockIdx.x * blockDim.x + threadIdx.x;
    if (i >= H * 96) return;
    int n = i / 96, k = i - n * 96;
    Wt0[i] = f2bf((k < F_IN) ? W1_0[k * H + n] : 0.f);
}

// ---------------- gather (aggregate) kernels ----------------

// layer 0: xb bf16 [N][96] (48 dwords); out = self+agg as bf16 [N][96]
__global__ void k_gather96(const unsigned int* __restrict__ xw,
                           const int* __restrict__ row_start, const int* __restrict__ esrc,
                           unsigned int* __restrict__ out) {
    int wave = threadIdx.x >> 6;
    int lane = threadIdx.x & 63;
    int node = blockIdx.x * 4 + wave;
    int s = row_start[node], e = row_start[node + 1];
    bool act = lane < 48;
    unsigned int su = act ? xw[node * 48 + lane] : 0u;
    float aA[8], aB[8];
#pragma unroll
    for (int j = 0; j < 8; ++j) { aA[j] = 0.f; aB[j] = 0.f; }
    aA[0] = bf_lo(su); aB[0] = bf_hi(su);
    int p = s;
    for (; p + 16 <= e; p += 16) {
        int idx[16];
#pragma unroll
        for (int j = 0; j < 16; ++j) idx[j] = esrc[p + j];
        unsigned int u[16];
#pragma unroll
        for (int j = 0; j < 16; ++j) u[j] = act ? xw[idx[j] * 48 + lane] : 0u;
#pragma unroll
        for (int j = 0; j < 16; ++j) { aA[j & 7] += bf_lo(u[j]); aB[j & 7] += bf_hi(u[j]); }
    }
    for (; p + 4 <= e; p += 4) {
        int i0 = esrc[p], i1 = esrc[p + 1], i2 = esrc[p + 2], i3 = esrc[p + 3];
        unsigned int u0 = act ? xw[i0 * 48 + lane] : 0u;
        unsigned int u1 = act ? xw[i1 * 48 + lane] : 0u;
        unsigned int u2 = act ? xw[i2 * 48 + lane] : 0u;
        unsigned int u3 = act ? xw[i3 * 48 + lane] : 0u;
        aA[0] += bf_lo(u0); aB[0] += bf_hi(u0); aA[1] += bf_lo(u1); aB[1] += bf_hi(u1);
        aA[2] += bf_lo(u2); aB[2] += bf_hi(u2); aA[3] += bf_lo(u3); aB[3] += bf_hi(u3);
    }
    for (; p < e; ++p) {
        unsigned int u = act ? xw[esrc[p] * 48 + lane] : 0u;
        aA[0] += bf_lo(u); aB[0] += bf_hi(u);
    }
    if (act) {
        float rx = ((aA[0] + aA[1]) + (aA[2] + aA[3])) + ((aA[4] + aA[5]) + (aA[6] + aA[7]));
        float ry = ((aB[0] + aB[1]) + (aB[2] + aB[3])) + ((aB[4] + aB[5]) + (aB[6] + aB[7]));
        out[node * 48 + lane] = (unsigned int)f2bf(rx) | ((unsigned int)f2bf(ry) << 16);
    }
}

// layers 1..4: hb bf16 [N][128] row-major; 16 outstanding row loads
__global__ void k_gather128b(const unsigned int* __restrict__ hw,
                             const int* __restrict__ row_start, const int* __restrict__ esrc,
                             unsigned int* __restrict__ aggb) {
    int wave = threadIdx.x >> 6;
    int lane = threadIdx.x & 63;
    int node = blockIdx.x * 4 + wave;
    int s = row_start[node], e = row_start[node + 1];
    unsigned int su = hw[node * 64 + lane];
    float aA[8], aB[8];
#pragma unroll
    for (int j = 0; j < 8; ++j) { aA[j] = 0.f; aB[j] = 0.f; }
    aA[0] = bf_lo(su); aB[0] = bf_hi(su);
    int p = s;
    for (; p + 16 <= e; p += 16) {
        int idx[16];
#pragma unroll
        for (int j = 0; j < 16; ++j) idx[j] = esrc[p + j];
        unsigned int u[16];
#pragma unroll
        for (int j = 0; j < 16; ++j) u[j] = hw[idx[j] * 64 + lane];
#pragma unroll
        for (int j = 0; j < 16; ++j) { aA[j & 7] += bf_lo(u[j]); aB[j & 7] += bf_hi(u[j]); }
    }
    for (; p + 4 <= e; p += 4) {
        int i0 = esrc[p], i1 = esrc[p + 1], i2 = esrc[p + 2], i3 = esrc[p + 3];
        unsigned int u0 = hw[i0 * 64 + lane];
        unsigned int u1 = hw[i1 * 64 + lane];
        unsigned int u2 = hw[i2 * 64 + lane];
        unsigned int u3 = hw[i3 * 64 + lane];
        aA[0] += bf_lo(u0); aB[0] += bf_hi(u0); aA[1] += bf_lo(u1); aB[1] += bf_hi(u1);
        aA[2] += bf_lo(u2); aB[2] += bf_hi(u2); aA[3] += bf_lo(u3); aB[3] += bf_hi(u3);
    }
    for (; p < e; ++p) {
        unsigned int u = hw[esrc[p] * 64 + lane];
        aA[0] += bf_lo(u); aB[0] += bf_hi(u);
    }
    float rx = ((aA[0] + aA[1]) + (aA[2] + aA[3])) + ((aA[4] + aA[5]) + (aA[6] + aA[7]));
    float ry = ((aB[0] + aB[1]) + (aB[2] + aB[3])) + ((aB[4] + aB[5]) + (aB[6] + aB[7]));
    aggb[node * 64 + lane] = (unsigned int)f2bf(rx) | ((unsigned int)f2bf(ry) << 16);
}

// ---------------- fused 2-GEMM MLP (MFMA, bf16) ----------------

template <int NK1>
__global__ __launch_bounds__(256) void k_mlp(const short* __restrict__ A,
                                             const short* __restrict__ Wt1,
                                             const float* __restrict__ b1v,
                                             const short* __restrict__ Wt2,
                                             const float* __restrict__ b2v,
                                             unsigned short* __restrict__ out,
                                             float* __restrict__ gsum,
                                             float* __restrict__ gss) {
    const int K1 = NK1 * 32;
    __shared__ unsigned short act1[64 * H];  // 16 KB
    __shared__ float lsum[H], lss[H];
    if (threadIdx.x < H) { lsum[threadIdx.x] = 0.f; lss[threadIdx.x] = 0.f; }
    int wave = threadIdx.x >> 6, lane = threadIdx.x & 63;
    int r0 = blockIdx.x * 64 + wave * 16;
    int lm = lane & 15, lk = lane >> 4;
    int arow = r0 + lm;
    if (arow >= N_NODES) arow = N_NODES - 1;
    const short8* Arow = (const short8*)(A + (size_t)arow * K1);
    f32x4v acc[8];
#pragma unroll
    for (int n = 0; n < 8; ++n) {
        float bv = b1v[n * 16 + lm];
        acc[n] = (f32x4v){bv, bv, bv, bv};
    }
#pragma unroll
    for (int ks = 0; ks < NK1; ++ks) {
        short8 af = Arow[ks * 4 + lk];
#pragma unroll
        for (int n = 0; n < 8; ++n) {
            const short8* Brow = (const short8*)(Wt1 + (size_t)(n * 16 + lm) * K1);
            short8 bfr = Brow[ks * 4 + lk];
            acc[n] = __builtin_amdgcn_mfma_f32_16x16x32_bf16(af, bfr, acc[n], 0, 0, 0);
        }
    }
#pragma unroll
    for (int n = 0; n < 8; ++n) {
        int colb = (n * 16 + lm) * 2;
#pragma unroll
        for (int rg = 0; rg < 4; ++rg) {
            int rl = wave * 16 + lk * 4 + rg;
            int byte = (rl * 256 + colb) ^ ((rl & 7) << 4);
            *(unsigned short*)((char*)act1 + byte) = f2bf(fmaxf(acc[n][rg], 0.f));
        }
    }
    __syncthreads();
    f32x4v acc2[8];
#pragma unroll
    for (int n = 0; n < 8; ++n) {
        float bv = b2v[n * 16 + lm];
        acc2[n] = (f32x4v){bv, bv, bv, bv};
    }
    int rlr = wave * 16 + lm;
#pragma unroll
    for (int ks = 0; ks < 4; ++ks) {
        int byte = (rlr * 256 + ks * 64 + lk * 16) ^ ((rlr & 7) << 4);
        short8 af = *(const short8*)((char*)act1 + byte);
#pragma unroll
        for (int n = 0; n < 8; ++n) {
            const short8* Brow = (const short8*)(Wt2 + (size_t)(n * 16 + lm) * H);
            short8 bfr = Brow[ks * 4 + lk];
            acc2[n] = __builtin_amdgcn_mfma_f32_16x16x32_bf16(af, bfr, acc2[n], 0, 0, 0);
        }
    }
#pragma unroll
    for (int n = 0; n < 8; ++n) {
        int col = n * 16 + lm;
        float s = 0.f, q = 0.f;
#pragma unroll
        for (int rg = 0; rg < 4; ++rg) {
            int r = r0 + lk * 4 + rg;
            if (r < N_NODES) {
                float v = fmaxf(acc2[n][rg], 0.f);
                out[(size_t)r * H + col] = f2bf(v);
                s += v;
                q += v * v;
            }
        }
        atomicAdd(&lsum[col], s);
        atomicAdd(&lss[col], q);
    }
    __syncthreads();
    if (threadIdx.x < H) {
        atomicAdd(&gsum[threadIdx.x], lsum[threadIdx.x]);
        atomicAdd(&gss[threadIdx.x], lss[threadIdx.x]);
    }
}

// ---------------- BN ----------------

__global__ void k_bnfinal(float* __restrict__ gsum, float* __restrict__ gss,
                          const float* __restrict__ gamma, const float* __restrict__ beta,
                          float* __restrict__ scale, float* __restrict__ shift) {
    int c = threadIdx.x;
    const float inv_n = 1.f / (float)N_NODES;
    float sv = gsum[c], qv = gss[c];
    gsum[c] = 0.f;
    gss[c] = 0.f;
    float mu = sv * inv_n;
    float var = fmaxf(qv * inv_n - mu * mu, 0.f);
    float sc = gamma[c] * rsqrtf(var + BN_EPS);
    scale[c] = sc;
    shift[c] = beta[c] - mu * sc;
}

// hb = bf16( (RES? bf(hb):0) + bf(act)*scale + shift )   — bf16-only residual state
template <bool RES>
__global__ void k_bnapply(const uint2* __restrict__ vb, const float* __restrict__ scale,
                          const float* __restrict__ shift, uint2* __restrict__ hb) {
    int idx = blockIdx.x * blockDim.x + threadIdx.x;  // 4-elem index
    if (idx >= N_NODES * H / 4) return;
    int c4 = idx & 31;
    uint2 pv = vb[idx];
    float4 val = make_float4(bf_lo(pv.x), bf_hi(pv.x), bf_lo(pv.y), bf_hi(pv.y));
    float4 sc = reinterpret_cast<const float4*>(scale)[c4];
    float4 sh = reinterpret_cast<const float4*>(shift)[c4];
    float4 r;
    r.x = val.x * sc.x + sh.x;
    r.y = val.y * sc.y + sh.y;
    r.z = val.z * sc.z + sh.z;
    r.w = val.w * sc.w + sh.w;
    if (RES) {
        uint2 hv = hb[idx];
        r.x += bf_lo(hv.x); r.y += bf_hi(hv.x); r.z += bf_lo(hv.y); r.w += bf_hi(hv.y);
    }
    uint2 pk;
    pk.x = (unsigned int)f2bf(r.x) | ((unsigned int)f2bf(r.y) << 16);
    pk.y = (unsigned int)f2bf(r.z) | ((unsigned int)f2bf(r.w) << 16);
    hb[idx] = pk;
}

// ---------------- pooling + head ----------------

__global__ void k_bounds(const int* __restrict__ batch, int* __restrict__ row_begin) {
    int i = blockIdx.x * blockDim.x + threadIdx.x;
    if (i >= N_NODES) return;
    int bi = batch[i];
    int bp = (i == 0) ? -1 : batch[i - 1];
    for (int g = bp + 1; g <= bi; ++g) row_begin[g] = i;
    if (i == N_NODES - 1) {
        for (int g = bi + 1; g <= N_GRAPHS; ++g) row_begin[g] = N_NODES;
    }
}

// fused: h4 = bf(hb3) + scale*bf(act) + shift on the fly, then mean/max pool.
// 256 threads: 2-way node-range split + LDS reduce.
__global__ __launch_bounds__(256) void k_pool_f(const unsigned short* __restrict__ act,
                                                const float* __restrict__ scale,
                                                const float* __restrict__ shift,
                                                const unsigned short* __restrict__ hb3,
                                                const int* __restrict__ row_begin,
                                                float* __restrict__ pooled) {
    __shared__ float ssum[256], smax[256];
    int g = blockIdx.x;
    int c = threadIdx.x & 127;
    int half = threadIdx.x >> 7;
    float sc = scale[c], sh = shift[c];
    int s = row_begin[g], e = row_begin[g + 1];
    float sum = 0.f, mx = -FLT_MAX;
    for (int i = s + half; i < e; i += 2) {
        float v = bf1(hb3[(size_t)i * H + c]) + sc * bf1(act[(size_t)i * H + c]) + sh;
        sum += v;
        mx = fmaxf(mx, v);
    }
    ssum[threadIdx.x] = sum;
    smax[threadIdx.x] = mx;
    __syncthreads();
    if (threadIdx.x < 128) {
        float fs = ssum[c] + ssum[128 + c];
        float fm = fmaxf(smax[c], smax[128 + c]);
        int cnt = e - s;
        pooled[g * 256 + c]       = (cnt > 0) ? fs / (float)cnt : 0.f;
        pooled[g * 256 + 128 + c] = (cnt > 0) ? fm : 0.f;
    }
}

__global__ void k_final(const float* __restrict__ pooled, const float* __restrict__ Wf,
                        const float* __restrict__ bf, float* __restrict__ out) {
    __shared__ float ps[256];
    int g = blockIdx.x, c = threadIdx.x;
    ps[c] = pooled[g * 256 + c];
    ps[128 + c] = pooled[g * 256 + 128 + c];
    __syncthreads();
    float acc = bf[c];
#pragma unroll 8
    for (int k = 0; k < 256; ++k) acc += ps[k] * Wf[k * H + c];
    out[g * H + c] = acc;
}

// ---------------- launcher ----------------

extern "C" void kernel_launch(void* const* d_in, const int* in_sizes, int n_in,
                              void* d_out, int out_size, void* d_ws, size_t ws_size,
                              hipStream_t stream) {
    const float* x     = (const float*)d_in[0];
    const int*   ei    = (const int*)d_in[1];
    const int*   src   = ei;
    const int*   dst   = ei + N_EDGES;
    const int*   batch = (const int*)d_in[2];
    const float* W1_0  = (const float*)d_in[3];
    const float* b1_0  = (const float*)d_in[4];
    const float* W2_0  = (const float*)d_in[5];
    const float* b2_0  = (const float*)d_in[6];
    const float* W1    = (const float*)d_in[7];
    const float* b1    = (const float*)d_in[8];
    const float* W2    = (const float*)d_in[9];
    const float* b2    = (const float*)d_in[10];
    const float* gamma = (const float*)d_in[11];
    const float* beta  = (const float*)d_in[12];
    const float* Wf    = (const float*)d_in[13];
    const float* bf    = (const float*)d_in[14];
    float* out = (float*)d_out;

    char* ws = (char*)d_ws;
    size_t off = 0;
    auto alloc = [&](size_t bytes) -> void* {
        void* p = ws + off;
        off = (off + bytes + 255) & ~(size_t)255;
        return p;
    };

    uint2* hb   = (uint2*)alloc((size_t)N_NODES * H * 2);
    unsigned int*   aggb  = (unsigned int*)alloc((size_t)N_NODES * H * 2);
    unsigned short* act2b = (unsigned short*)alloc((size_t)N_NODES * H * 2);
    unsigned short* xb    = (unsigned short*)alloc((size_t)N_NODES * 96 * 2);
    unsigned int*   agg0b = (unsigned int*)alloc((size_t)N_NODES * 48 * 4);
    unsigned short* Wtall = (unsigned short*)alloc((size_t)9 * H * H * 2);
    unsigned short* Wt0   = (unsigned short*)alloc((size_t)H * 96 * 2);
    int* row_start = (int*)alloc((size_t)(N_NODES + 1) * 4);
    int* esrc      = (int*)alloc((size_t)N_EDGES * 4);
    unsigned int* ebuf = (unsigned int*)alloc((size_t)N_EDGES * 4);
    int* bofs      = (int*)alloc((size_t)P3_BLOCKS * NBUCKETS * 4);
    int* btot      = (int*)alloc((size_t)NBUCKETS * 4);
    int* bbase     = (int*)alloc((size_t)(NBUCKETS + 1) * 4);
    float* gsum  = (float*)alloc(H * 4);   // gsum+gss contiguous (512B each, 256-aligned)
    float* gss   = (float*)alloc(H * 4);
    float* scale = (float*)alloc(H * 4);
    float* shift = (float*)alloc(H * 4);
    int* row_begin = (int*)alloc((size_t)(N_GRAPHS + 1) * 4);
    float* pooled  = (float*)alloc((size_t)N_GRAPHS * 256 * 4);

    // ---- prep ----
    k_cast_x<<<(N_NODES * 96 + 255) / 256, 256, 0, stream>>>(x, xb);
    k_cast_w<<<(9 * H * H + 255) / 256, 256, 0, stream>>>(W2_0, W1, W2, Wtall);
    k_cast_w0<<<(H * 96 + 255) / 256, 256, 0, stream>>>(W1_0, Wt0);

    // ---- CSR build (no global atomics) ----
    k_hist<<<P3_BLOCKS, 256, 0, stream>>>(dst, bofs);
    k_scan_a<<<NBUCKETS, 256, 0, stream>>>(bofs, btot);
    k_scan_b<<<1, 1024, 0, stream>>>(btot, bbase, row_start);
    k_p3b<<<P3_BLOCKS, 256, 0, stream>>>(src, dst, bofs, bbase, ebuf);
    k_p4<<<NBUCKETS, 256, 0, stream>>>(bbase, ebuf, esrc, row_start);

    // zero BN accumulators once per call (bnfinal self-resets for later layers);
    // gsum and gss are contiguous -> single memset
    hipMemsetAsync(gsum, 0, 2 * H * 4, stream);

    const int mfma_grid = (N_NODES + 63) / 64;

    // ---- layer 0 (78 -> 128, no residual) ----
    k_gather96<<<N_NODES / 4, 256, 0, stream>>>((const unsigned int*)xb, row_start, esrc, agg0b);
    k_mlp<3><<<mfma_grid, 256, 0, stream>>>((const short*)agg0b, (const short*)Wt0, b1_0,
                                            (const short*)Wtall, b2_0, act2b, gsum, gss);
    k_bnfinal<<<1, 128, 0, stream>>>(gsum, gss, gamma, beta, scale, shift);
    k_bnapply<false><<<N_NODES * H / 4 / 256, 256, 0, stream>>>((const uint2*)act2b,
                                                                scale, shift, hb);

    // ---- layers 1..4 (residual) ----
    for (int l = 0; l < 4; ++l) {
        k_gather128b<<<N_NODES / 4, 256, 0, stream>>>((const unsigned int*)hb, row_start,
                                                      esrc, aggb);
        k_mlp<4><<<mfma_grid, 256, 0, stream>>>((const short*)aggb,
                                                (const short*)(Wtall + (1 + l) * H * H),
                                                b1 + l * H,
                                                (const short*)(Wtall + (5 + l) * H * H),
                                                b2 + l * H, act2b, gsum, gss);
        k_bnfinal<<<1, 128, 0, stream>>>(gsum, gss, gamma + (l + 1) * H, beta + (l + 1) * H,
                                         scale, shift);
        if (l < 3) {
            k_bnapply<true><<<N_NODES * H / 4 / 256, 256, 0, stream>>>((const uint2*)act2b,
                                                                       scale, shift, hb);
        }
        // l == 3: bnapply fused into k_pool_f below
    }

    // ---- pooling + head ----
    k_bounds<<<(N_NODES + 255) / 256, 256, 0, stream>>>(batch, row_begin);
    k_pool_f<<<N_GRAPHS, 256, 0, stream>>>(act2b, scale, shift,
                                           (const unsigned short*)hb, row_begin, pooled);
    k_final<<<N_GRAPHS, 128, 0, stream>>>(pooled, Wf, bf, out);
}